// Round 4
// baseline (239.664 us; speedup 1.0000x reference)
//
#include <hip/hip_runtime.h>
#include <hip/hip_bf16.h>

#define BB 8
#define NN 1024
#define DD 256
#define RR 12
#define BN (BB * NN)  // 8192
#define ICH 8
#define CCH (NN / ICH)  // 128

typedef __attribute__((ext_vector_type(8))) short short8v;
typedef __attribute__((ext_vector_type(4))) float f32x4;

static __device__ __forceinline__ ushort f2bf(float f) {
  union { float f; uint u; } v; v.f = f;
  uint r = v.u + 0x7FFF + ((v.u >> 16) & 1);
  return (ushort)(r >> 16);
}
static __device__ __forceinline__ uint pack2(float a, float b) {
  return (uint)f2bf(a) | ((uint)f2bf(b) << 16);
}

// ---------------- K1: prepW (blocks 0..15) + V precompute (blocks 16..67) ----
// V[half][c][k] = sum_d W[k][d] * X[d],  X = a-half (c==0) or A_rel[c-1]-half.
__global__ __launch_bounds__(256) void k_prep(const float* __restrict__ W,
                                              const float* __restrict__ a,
                                              const float* __restrict__ A_rel,
                                              ushort* __restrict__ WTb,
                                              float* __restrict__ Vt) {
  __shared__ float Ls[64][65];
  int blk = blockIdx.x, tid = threadIdx.x;
  if (blk < 16) {
    int k0 = (blk & 3) * 64, d0 = (blk >> 2) * 64;
    int rr = tid >> 4, c = (tid & 15) * 4;
#pragma unroll
    for (int p = 0; p < 4; ++p) {
      int row = p * 16 + rr;
      float4 v = *(const float4*)&W[(k0 + row) * DD + d0 + c];
      Ls[row][c] = v.x; Ls[row][c + 1] = v.y; Ls[row][c + 2] = v.z; Ls[row][c + 3] = v.w;
    }
    __syncthreads();
    int r2 = tid >> 3, cc = (tid & 7) * 8;
#pragma unroll
    for (int p = 0; p < 2; ++p) {
      int d = p * 32 + r2;
      uint4 q;
      q.x = pack2(Ls[cc + 0][d], Ls[cc + 1][d]);
      q.y = pack2(Ls[cc + 2][d], Ls[cc + 3][d]);
      q.z = pack2(Ls[cc + 4][d], Ls[cc + 5][d]);
      q.w = pack2(Ls[cc + 6][d], Ls[cc + 7][d]);
      *(uint4*)&WTb[(d0 + d) * DD + k0 + cc] = q;
    }
  } else {
    int idx = blk - 16;            // 0..51
    int half = idx >= 26 ? 1 : 0;
    int c = idx - half * 26;       // 0..25 -> but only 0..12 used per half
    if (c >= 13) return;           // (blocks 16..67 map 2x26; only 13 used)
    int k = tid;
    float acc = 0.f;
    for (int d4 = 0; d4 < DD / 4; ++d4) {
      float4 w4 = *(const float4*)&W[k * DD + d4 * 4];
      float4 x4;
      if (c == 0) x4 = *(const float4*)&a[half * DD + d4 * 4];
      else        x4 = *(const float4*)&A_rel[(c - 1) * 2 * DD + half * DD + d4 * 4];
      acc += w4.x * x4.x + w4.y * x4.y + w4.z * x4.z + w4.w * x4.w;
    }
    Vt[(half * 13 + c) * DD + k] = acc;
  }
}

// ---------------- K2: Wh1 = h1@W (MFMA, blocks 0..255) + s/r proj (256..511) --
__global__ __launch_bounds__(256) void k_wh_proj(const float* __restrict__ h0,
                                                 const float* __restrict__ h1,
                                                 const ushort* __restrict__ WTb,
                                                 const float* __restrict__ Vt,
                                                 float* __restrict__ Wh1,
                                                 float* __restrict__ s0, float* __restrict__ s1,
                                                 float* __restrict__ r0, float* __restrict__ r1) {
  __shared__ uint4 AswQ[64 * 8];
  __shared__ uint4 BswQ[128 * 8];
  int blk = blockIdx.x, tid = threadIdx.x;
  if (blk < 256) {
    int n0 = (blk & 1) * 128, i0 = (blk >> 1) * 64;
    int r = tid >> 3, cs = tid & 7;
    int lane = tid & 63, wid = tid >> 6;
    int wm = wid >> 1, wn = wid & 1;
    int lr = lane & 15, g = lane >> 4;
    f32x4 acc[2][4] = {};
    for (int k0 = 0; k0 < DD; k0 += 64) {
#pragma unroll
      for (int p = 0; p < 2; ++p) {
        int row = p * 32 + r;
        const float* src = h1 + (long)(i0 + row) * DD + k0 + cs * 8;
        float4 v0 = *(const float4*)src;
        float4 v1 = *(const float4*)(src + 4);
        uint4 q;
        q.x = pack2(v0.x, v0.y); q.y = pack2(v0.z, v0.w);
        q.z = pack2(v1.x, v1.y); q.w = pack2(v1.z, v1.w);
        AswQ[row * 8 + (cs ^ (row & 7))] = q;
      }
#pragma unroll
      for (int p = 0; p < 4; ++p) {
        int row = p * 32 + r;
        uint4 q = *(const uint4*)(WTb + (long)(n0 + row) * DD + k0 + cs * 8);
        BswQ[row * 8 + (cs ^ (row & 7))] = q;
      }
      __syncthreads();
#pragma unroll
      for (int ks = 0; ks < 2; ++ks) {
        short8v af[2], bfr[4];
        int slot = ks * 4 + g;
#pragma unroll
        for (int mi = 0; mi < 2; ++mi) {
          int row = wm * 32 + mi * 16 + lr;
          af[mi] = *reinterpret_cast<const short8v*>(&AswQ[row * 8 + (slot ^ (row & 7))]);
        }
#pragma unroll
        for (int ni = 0; ni < 4; ++ni) {
          int row = wn * 64 + ni * 16 + lr;
          bfr[ni] = *reinterpret_cast<const short8v*>(&BswQ[row * 8 + (slot ^ (row & 7))]);
        }
#pragma unroll
        for (int mi = 0; mi < 2; ++mi)
#pragma unroll
          for (int ni = 0; ni < 4; ++ni)
            acc[mi][ni] = __builtin_amdgcn_mfma_f32_16x16x32_bf16(af[mi], bfr[ni], acc[mi][ni], 0, 0, 0);
      }
      __syncthreads();
    }
#pragma unroll
    for (int mi = 0; mi < 2; ++mi)
#pragma unroll
      for (int ni = 0; ni < 4; ++ni)
#pragma unroll
        for (int q = 0; q < 4; ++q) {
          int row = i0 + wm * 32 + mi * 16 + g * 4 + q;
          int col = n0 + wn * 64 + ni * 16 + lr;
          Wh1[(long)row * DD + col] = acc[mi][ni][q];
        }
  } else {
    int w = ((blk - 256) << 2) + (tid >> 6);  // wave 0..1023
    int lane = tid & 63;
    for (int it = 0; it < 16; ++it) {
      int row = w + (it << 10);               // 0..16383
      int mat = row >> 13, rr = row & (BN - 1);
      const float* h = mat ? h1 : h0;
      float4 h4 = *(const float4*)&h[(long)rr * DD + lane * 4];
#pragma unroll
      for (int c = 0; c < 13; ++c) {
        float4 v4 = *(const float4*)&Vt[(mat * 13 + c) * DD + lane * 4];
        float p = h4.x * v4.x + h4.y * v4.y + h4.z * v4.z + h4.w * v4.w;
#pragma unroll
        for (int off = 32; off; off >>= 1) p += __shfl_xor(p, off);
        if (lane == 0) {
          if (c == 0) (mat ? s1 : s0)[rr] = p;
          else (mat ? r1 : r0)[(c - 1) * BN + rr] = p;
        }
      }
    }
  }
}

// ---------------- K3: scores (blocks 0..1023) + Wh1->WhbT transpose (1024..1535)
__global__ __launch_bounds__(256) void k_trans_scores(const float* __restrict__ Wh1,
                                                      ushort* __restrict__ WhT,
                                                      const int* __restrict__ madj,
                                                      const int* __restrict__ adj,
                                                      const float* __restrict__ s0,
                                                      const float* __restrict__ s1,
                                                      const float* __restrict__ r0,
                                                      const float* __restrict__ r1,
                                                      float* __restrict__ S,
                                                      float* __restrict__ pm,
                                                      float* __restrict__ pl) {
  union Sm {
    float Ls[64][65];
    struct { float s0c[ICH]; float r0c[RR][ICH]; } sc;
  };
  __shared__ Sm sm;
  int blk = blockIdx.x, tid = threadIdx.x;
  if (blk < 1024) {
    int b = blk & 7, c = blk >> 3;
    int j4 = tid * 4;
    int i0 = c * ICH;
    if (tid < (RR + 1) * ICH) {
      int v = tid / ICH, i = tid % ICH;
      float x = (v == 0) ? s0[b * NN + i0 + i] : r0[(v - 1) * BN + b * NN + i0 + i];
      if (v == 0) sm.sc.s0c[i] = x; else sm.sc.r0c[v - 1][i] = x;
    }
    __syncthreads();
    float4 s14 = *(const float4*)&s1[b * NN + j4];
    float rel[ICH][4] = {};
    for (int r = 0; r < RR; ++r) {
      float4 r1v = *(const float4*)&r1[r * BN + b * NN + j4];
#pragma unroll
      for (int i = 0; i < ICH; ++i) {
        int4 mv = *(const int4*)&madj[(((long)r * BB + b) * NN + i0 + i) * NN + j4];
        float r0v = sm.sc.r0c[r][i];
        float t0 = r0v + r1v.x; t0 = t0 >= 0.f ? t0 : 0.2f * t0;
        float t1 = r0v + r1v.y; t1 = t1 >= 0.f ? t1 : 0.2f * t1;
        float t2 = r0v + r1v.z; t2 = t2 >= 0.f ? t2 : 0.2f * t2;
        float t3 = r0v + r1v.w; t3 = t3 >= 0.f ? t3 : 0.2f * t3;
        if (mv.x > 0) rel[i][0] += t0;
        if (mv.y > 0) rel[i][1] += t1;
        if (mv.z > 0) rel[i][2] += t2;
        if (mv.w > 0) rel[i][3] += t3;
      }
    }
    float m0 = -3.0e38f, m1 = -3.0e38f, m2 = -3.0e38f, m3 = -3.0e38f;
    float l0 = 0.f, l1 = 0.f, l2 = 0.f, l3 = 0.f;
#pragma unroll
    for (int i = 0; i < ICH; ++i) {
      int4 av = *(const int4*)&adj[((long)b * NN + i0 + i) * NN + j4];
      float s0v = sm.sc.s0c[i];
      float4 sc;
      { float e = s0v + s14.x; e = e >= 0.f ? e : 0.2f * e;
        sc.x = (av.x > 0 ? e : -9e15f) + 0.01f * rel[i][0]; }
      { float e = s0v + s14.y; e = e >= 0.f ? e : 0.2f * e;
        sc.y = (av.y > 0 ? e : -9e15f) + 0.01f * rel[i][1]; }
      { float e = s0v + s14.z; e = e >= 0.f ? e : 0.2f * e;
        sc.z = (av.z > 0 ? e : -9e15f) + 0.01f * rel[i][2]; }
      { float e = s0v + s14.w; e = e >= 0.f ? e : 0.2f * e;
        sc.w = (av.w > 0 ? e : -9e15f) + 0.01f * rel[i][3]; }
      *(float4*)&S[((long)b * NN + i0 + i) * NN + j4] = sc;
      float nm;
      nm = fmaxf(m0, sc.x); l0 = l0 * __expf(m0 - nm) + __expf(sc.x - nm); m0 = nm;
      nm = fmaxf(m1, sc.y); l1 = l1 * __expf(m1 - nm) + __expf(sc.y - nm); m1 = nm;
      nm = fmaxf(m2, sc.z); l2 = l2 * __expf(m2 - nm) + __expf(sc.z - nm); m2 = nm;
      nm = fmaxf(m3, sc.w); l3 = l3 * __expf(m3 - nm) + __expf(sc.w - nm); m3 = nm;
    }
    *(float4*)&pm[(long)c * BN + b * NN + j4] = make_float4(m0, m1, m2, m3);
    *(float4*)&pl[(long)c * BN + b * NN + j4] = make_float4(l0, l1, l2, l3);
  } else {
    int t = blk - 1024;
    int d0 = (t & 3) * 64, i0 = ((t >> 2) & 15) * 64, z = t >> 6;
    int rr = tid >> 4, c = (tid & 15) * 4;
#pragma unroll
    for (int p = 0; p < 4; ++p) {
      int row = p * 16 + rr;
      float4 v = *(const float4*)&Wh1[(long)(z * NN + i0 + row) * DD + d0 + c];
      sm.Ls[row][c] = v.x; sm.Ls[row][c + 1] = v.y;
      sm.Ls[row][c + 2] = v.z; sm.Ls[row][c + 3] = v.w;
    }
    __syncthreads();
    int r2 = tid >> 3, cc = (tid & 7) * 8;
#pragma unroll
    for (int p = 0; p < 2; ++p) {
      int d = p * 32 + r2;
      uint4 q;
      q.x = pack2(sm.Ls[cc + 0][d], sm.Ls[cc + 1][d]);
      q.y = pack2(sm.Ls[cc + 2][d], sm.Ls[cc + 3][d]);
      q.z = pack2(sm.Ls[cc + 4][d], sm.Ls[cc + 5][d]);
      q.w = pack2(sm.Ls[cc + 6][d], sm.Ls[cc + 7][d]);
      *(uint4*)&WhT[(long)z * DD * NN + (long)(d0 + d) * NN + i0 + cc] = q;
    }
  }
}

// ---------------- K4: combine partial stats (parallel, 16 thr/col) ----------
__global__ __launch_bounds__(256) void k_combine(const float* __restrict__ pm,
                                                 const float* __restrict__ pl,
                                                 float* __restrict__ mf,
                                                 float* __restrict__ li) {
  __shared__ float sm_m[256], sm_l[256];
  int tid = threadIdx.x;
  int col_l = tid & 15, seg = tid >> 4;
  int col = blockIdx.x * 16 + col_l;
  float m = -3.0e38f, l = 0.f;
#pragma unroll
  for (int q = 0; q < 8; ++q) {
    int c = seg * 8 + q;
    float mc = pm[(long)c * BN + col];
    float lc = pl[(long)c * BN + col];
    float nm = fmaxf(m, mc);
    l = l * __expf(m - nm) + lc * __expf(mc - nm);
    m = nm;
  }
  sm_m[tid] = m; sm_l[tid] = l;
  __syncthreads();
  for (int s = 8; s; s >>= 1) {
    if (seg < s) {
      float ma = sm_m[tid], la = sm_l[tid];
      float mb = sm_m[tid + s * 16], lb = sm_l[tid + s * 16];
      float nm = fmaxf(ma, mb);
      sm_m[tid] = nm;
      sm_l[tid] = la * __expf(ma - nm) + lb * __expf(mb - nm);
    }
    __syncthreads();
  }
  if (seg == 0) {
    mf[col] = sm_m[tid];
    li[col] = 1.0f / sm_l[tid];
  }
}

// ---------------- K5: out = elu( P @ Wh1 ), BM=32 BN=128 ----------------
__global__ __launch_bounds__(256) void k_av(const float* __restrict__ S,
                                            const float* __restrict__ mf,
                                            const float* __restrict__ li,
                                            const ushort* __restrict__ WhT,
                                            float* __restrict__ out) {
  __shared__ uint4 AswQ[32 * 8];
  __shared__ uint4 BswQ[128 * 8];
  int b = blockIdx.z;
  int i0 = blockIdx.y * 32;
  int n0 = blockIdx.x * 128;
  const float* Sb = S + (long)b * NN * NN;
  const ushort* Bb = WhT + (long)b * DD * NN;
  const float* mfb = mf + (long)b * NN;
  const float* lib = li + (long)b * NN;
  int tid = threadIdx.x;
  int r = tid >> 3, cs = tid & 7;
  int lane = tid & 63, wid = tid >> 6;
  int lr = lane & 15, g = lane >> 4;
  f32x4 acc[2][2] = {};
  for (int k0 = 0; k0 < NN; k0 += 64) {
    {
      const float* src = Sb + (long)(i0 + r) * NN + k0 + cs * 8;
      float4 v0 = *(const float4*)src;
      float4 v1 = *(const float4*)(src + 4);
      const float* mp = mfb + k0 + cs * 8;
      const float* lp = lib + k0 + cs * 8;
      float4 m0 = *(const float4*)mp, m1 = *(const float4*)(mp + 4);
      float4 l0 = *(const float4*)lp, l1 = *(const float4*)(lp + 4);
      v0.x = __expf(v0.x - m0.x) * l0.x;
      v0.y = __expf(v0.y - m0.y) * l0.y;
      v0.z = __expf(v0.z - m0.z) * l0.z;
      v0.w = __expf(v0.w - m0.w) * l0.w;
      v1.x = __expf(v1.x - m1.x) * l1.x;
      v1.y = __expf(v1.y - m1.y) * l1.y;
      v1.z = __expf(v1.z - m1.z) * l1.z;
      v1.w = __expf(v1.w - m1.w) * l1.w;
      uint4 q;
      q.x = pack2(v0.x, v0.y); q.y = pack2(v0.z, v0.w);
      q.z = pack2(v1.x, v1.y); q.w = pack2(v1.z, v1.w);
      AswQ[r * 8 + (cs ^ (r & 7))] = q;
    }
#pragma unroll
    for (int p = 0; p < 4; ++p) {
      int row = p * 32 + r;
      uint4 q = *(const uint4*)(Bb + (long)(n0 + row) * NN + k0 + cs * 8);
      BswQ[row * 8 + (cs ^ (row & 7))] = q;
    }
    __syncthreads();
#pragma unroll
    for (int ks = 0; ks < 2; ++ks) {
      short8v af[2], bfr[2];
      int slot = ks * 4 + g;
#pragma unroll
      for (int mi = 0; mi < 2; ++mi) {
        int row = mi * 16 + lr;
        af[mi] = *reinterpret_cast<const short8v*>(&AswQ[row * 8 + (slot ^ (row & 7))]);
      }
#pragma unroll
      for (int ni = 0; ni < 2; ++ni) {
        int row = wid * 32 + ni * 16 + lr;
        bfr[ni] = *reinterpret_cast<const short8v*>(&BswQ[row * 8 + (slot ^ (row & 7))]);
      }
#pragma unroll
      for (int mi = 0; mi < 2; ++mi)
#pragma unroll
        for (int ni = 0; ni < 2; ++ni)
          acc[mi][ni] = __builtin_amdgcn_mfma_f32_16x16x32_bf16(af[mi], bfr[ni], acc[mi][ni], 0, 0, 0);
    }
    __syncthreads();
  }
#pragma unroll
  for (int mi = 0; mi < 2; ++mi)
#pragma unroll
    for (int ni = 0; ni < 2; ++ni)
#pragma unroll
      for (int q = 0; q < 4; ++q) {
        int row = i0 + mi * 16 + g * 4 + q;
        int col = n0 + wid * 32 + ni * 16 + lr;
        float x = acc[mi][ni][q];
        x = x > 0.f ? x : expm1f(x);
        out[((long)b * NN + row) * DD + col] = x;
      }
}

extern "C" void kernel_launch(void* const* d_in, const int* in_sizes, int n_in,
                              void* d_out, int out_size, void* d_ws, size_t ws_size,
                              hipStream_t stream) {
  const float* h0 = (const float*)d_in[0];
  const float* h1 = (const float*)d_in[1];
  const int* madj = (const int*)d_in[2];
  const int* adj = (const int*)d_in[3];
  const float* W = (const float*)d_in[4];
  const float* a = (const float*)d_in[5];
  const float* A_rel = (const float*)d_in[6];
  float* out = (float*)d_out;

  float* ws = (float*)d_ws;
  float* Wh1 = ws;                          // 2,097,152
  float* S = Wh1 + (size_t)BN * DD;         // 8,388,608
  float* s0 = S + (size_t)BB * NN * NN;     // 8192
  float* s1 = s0 + BN;
  float* r0 = s1 + BN;                      // 98304
  float* r1 = r0 + RR * BN;
  float* pm = r1 + RR * BN;                 // 1,048,576
  float* pl = pm + (size_t)CCH * BN;        // 1,048,576
  float* mf = pl + (size_t)CCH * BN;        // 8192
  float* li = mf + BN;
  float* Vt = li + BN;                      // 6656
  ushort* WTb = (ushort*)(Vt + 26 * DD);    // 65536 ushort
  ushort* WhbT = WTb + DD * DD;             // 2,097,152 ushort

  k_prep<<<68, 256, 0, stream>>>(W, a, A_rel, WTb, Vt);
  k_wh_proj<<<512, 256, 0, stream>>>(h0, h1, WTb, Vt, Wh1, s0, s1, r0, r1);
  k_trans_scores<<<1536, 256, 0, stream>>>(Wh1, WhbT, madj, adj, s0, s1, r0, r1, S, pm, pl);
  k_combine<<<512, 256, 0, stream>>>(pm, pl, mf, li);
  k_av<<<dim3(2, NN / 32, BB), 256, 0, stream>>>(S, mf, li, WhbT, out);
}

// Round 6
// 178.958 us; speedup vs baseline: 1.3392x; 1.3392x over previous
//
#include <hip/hip_runtime.h>
#include <hip/hip_bf16.h>
#include <hip/hip_fp16.h>

#define BB 8
#define NN 1024
#define DD 256
#define RR 12
#define BN (BB * NN)  // 8192
#define ICH 8
#define CCH (NN / ICH)  // 128

typedef __attribute__((ext_vector_type(8))) short short8v;
typedef __attribute__((ext_vector_type(8))) _Float16 half8v;
typedef __attribute__((ext_vector_type(4))) float f32x4;
typedef __attribute__((ext_vector_type(4))) int int4v;

static __device__ __forceinline__ ushort f2bf(float f) {
  union { float f; uint u; } v; v.f = f;
  uint r = v.u + 0x7FFF + ((v.u >> 16) & 1);
  return (ushort)(r >> 16);
}
static __device__ __forceinline__ uint pack2(float a, float b) {
  return (uint)f2bf(a) | ((uint)f2bf(b) << 16);
}
static __device__ __forceinline__ ushort f2h(float f) {
  __half h = __float2half(f);  // RTN
  union { __half h; ushort u; } v; v.h = h;
  return v.u;
}

// ---------------- K1: prepW transpose (blocks 0..15) + Vt (16..67) ----------
// Vt[half*13+c][k] = sum_d W[k][d]*X[d]; X = a-half (c==0) else A_rel[c-1]-half.
__global__ __launch_bounds__(256) void k_prep(const float* __restrict__ W,
                                              const float* __restrict__ a,
                                              const float* __restrict__ A_rel,
                                              ushort* __restrict__ WTb,
                                              float* __restrict__ Vt) {
  __shared__ float Ls[64][65];
  int blk = blockIdx.x, tid = threadIdx.x;
  if (blk < 16) {
    int k0 = (blk & 3) * 64, d0 = (blk >> 2) * 64;
    int rr = tid >> 4, c = (tid & 15) * 4;
#pragma unroll
    for (int p = 0; p < 4; ++p) {
      int row = p * 16 + rr;
      float4 v = *(const float4*)&W[(k0 + row) * DD + d0 + c];
      Ls[row][c] = v.x; Ls[row][c + 1] = v.y; Ls[row][c + 2] = v.z; Ls[row][c + 3] = v.w;
    }
    __syncthreads();
    int r2 = tid >> 3, cc = (tid & 7) * 8;
#pragma unroll
    for (int p = 0; p < 2; ++p) {
      int d = p * 32 + r2;
      uint4 q;
      q.x = pack2(Ls[cc + 0][d], Ls[cc + 1][d]);
      q.y = pack2(Ls[cc + 2][d], Ls[cc + 3][d]);
      q.z = pack2(Ls[cc + 4][d], Ls[cc + 5][d]);
      q.w = pack2(Ls[cc + 6][d], Ls[cc + 7][d]);
      *(uint4*)&WTb[(d0 + d) * DD + k0 + cc] = q;
    }
  } else {
    int idx = blk - 16;             // 0..51
    int half = idx >= 26 ? 1 : 0;
    int c = idx - half * 26;
    if (c >= 13) return;
    int lane = tid & 63, w = tid >> 6;
    const float* X = (c == 0) ? &a[half * DD] : &A_rel[(c - 1) * 2 * DD + half * DD];
    float4 x4 = *(const float4*)&X[lane * 4];
    for (int kk = 0; kk < 64; ++kk) {
      int k = kk * 4 + w;
      float4 w4 = *(const float4*)&W[k * DD + lane * 4];
      float p = w4.x * x4.x + w4.y * x4.y + w4.z * x4.z + w4.w * x4.w;
#pragma unroll
      for (int off = 32; off; off >>= 1) p += __shfl_xor(p, off);
      if (lane == 0) Vt[(half * 13 + c) * DD + k] = p;
    }
  }
}

// ---------------- K2: per-node projections from h and Vt ----------------
__global__ __launch_bounds__(256) void k_proj(const float* __restrict__ h0,
                                              const float* __restrict__ h1,
                                              const float* __restrict__ Vt,
                                              float* __restrict__ s0, float* __restrict__ s1,
                                              float* __restrict__ r0, float* __restrict__ r1) {
  int wid = (blockIdx.x * 256 + threadIdx.x) >> 6;  // 0..16383
  int lane = threadIdx.x & 63;
  int mat = wid >> 13;
  int row = wid & (BN - 1);
  const float* h = mat ? h1 : h0;
  float4 h4 = *(const float4*)&h[(long)row * DD + lane * 4];
  float p[13];
#pragma unroll
  for (int c = 0; c < 13; ++c) {
    float4 v4 = *(const float4*)&Vt[(mat * 13 + c) * DD + lane * 4];
    p[c] = h4.x * v4.x + h4.y * v4.y + h4.z * v4.z + h4.w * v4.w;
  }
#pragma unroll
  for (int off = 32; off; off >>= 1)
#pragma unroll
    for (int c = 0; c < 13; ++c) p[c] += __shfl_xor(p[c], off);
  if (lane == 0) {
    if (mat == 0) {
      s0[row] = p[0];
      for (int c = 1; c < 13; ++c) r0[(c - 1) * BN + row] = p[c];
    } else {
      s1[row] = p[0];
      for (int c = 1; c < 13; ++c) r1[(c - 1) * BN + row] = p[c];
    }
  }
}

// ---------------- K3: Wh1 = h1 @ W  (bf16 MFMA, BM=64 BN=128) ----------------
__global__ __launch_bounds__(256) void k_mm_wh1(const float* __restrict__ h1,
                                                const ushort* __restrict__ WTb,
                                                float* __restrict__ Wh1) {
  __shared__ uint4 AswQ[64 * 8];
  __shared__ uint4 BswQ[128 * 8];
  int n0 = blockIdx.x * 128, i0 = blockIdx.y * 64;
  int tid = threadIdx.x;
  int r = tid >> 3, cs = tid & 7;
  int lane = tid & 63, wid = tid >> 6;
  int wm = wid >> 1, wn = wid & 1;
  int lr = lane & 15, g = lane >> 4;
  f32x4 acc[2][4] = {};
  for (int k0 = 0; k0 < DD; k0 += 64) {
#pragma unroll
    for (int p = 0; p < 2; ++p) {
      int row = p * 32 + r;
      const float* src = h1 + (long)(i0 + row) * DD + k0 + cs * 8;
      float4 v0 = *(const float4*)src;
      float4 v1 = *(const float4*)(src + 4);
      uint4 q;
      q.x = pack2(v0.x, v0.y); q.y = pack2(v0.z, v0.w);
      q.z = pack2(v1.x, v1.y); q.w = pack2(v1.z, v1.w);
      AswQ[row * 8 + (cs ^ (row & 7))] = q;
    }
#pragma unroll
    for (int p = 0; p < 4; ++p) {
      int row = p * 32 + r;
      uint4 q = *(const uint4*)(WTb + (long)(n0 + row) * DD + k0 + cs * 8);
      BswQ[row * 8 + (cs ^ (row & 7))] = q;
    }
    __syncthreads();
#pragma unroll
    for (int ks = 0; ks < 2; ++ks) {
      short8v af[2], bfr[4];
      int slot = ks * 4 + g;
#pragma unroll
      for (int mi = 0; mi < 2; ++mi) {
        int row = wm * 32 + mi * 16 + lr;
        af[mi] = *reinterpret_cast<const short8v*>(&AswQ[row * 8 + (slot ^ (row & 7))]);
      }
#pragma unroll
      for (int ni = 0; ni < 4; ++ni) {
        int row = wn * 64 + ni * 16 + lr;
        bfr[ni] = *reinterpret_cast<const short8v*>(&BswQ[row * 8 + (slot ^ (row & 7))]);
      }
#pragma unroll
      for (int mi = 0; mi < 2; ++mi)
#pragma unroll
        for (int ni = 0; ni < 4; ++ni)
          acc[mi][ni] = __builtin_amdgcn_mfma_f32_16x16x32_bf16(af[mi], bfr[ni], acc[mi][ni], 0, 0, 0);
    }
    __syncthreads();
  }
#pragma unroll
  for (int mi = 0; mi < 2; ++mi)
#pragma unroll
    for (int ni = 0; ni < 4; ++ni)
#pragma unroll
      for (int q = 0; q < 4; ++q) {
        int row = i0 + wm * 32 + mi * 16 + g * 4 + q;
        int col = n0 + wn * 64 + ni * 16 + lr;
        Wh1[(long)row * DD + col] = acc[mi][ni][q];
      }
}

// ---------------- K4: WhT[b][d][i] = bf16(Wh1[b][i][d]) ----------------
__global__ __launch_bounds__(256) void k_transWh(const float* __restrict__ Wh,
                                                 ushort* __restrict__ WhT) {
  __shared__ float Ls[64][65];
  int z = blockIdx.z;
  int d0 = blockIdx.x * 64, i0 = blockIdx.y * 64;
  int tid = threadIdx.x;
  int rr = tid >> 4, c = (tid & 15) * 4;
#pragma unroll
  for (int p = 0; p < 4; ++p) {
    int row = p * 16 + rr;
    float4 v = *(const float4*)&Wh[(long)(z * NN + i0 + row) * DD + d0 + c];
    Ls[row][c] = v.x; Ls[row][c + 1] = v.y; Ls[row][c + 2] = v.z; Ls[row][c + 3] = v.w;
  }
  __syncthreads();
  int r2 = tid >> 3, cc = (tid & 7) * 8;
#pragma unroll
  for (int p = 0; p < 2; ++p) {
    int d = p * 32 + r2;
    uint4 q;
    q.x = pack2(Ls[cc + 0][d], Ls[cc + 1][d]);
    q.y = pack2(Ls[cc + 2][d], Ls[cc + 3][d]);
    q.z = pack2(Ls[cc + 4][d], Ls[cc + 5][d]);
    q.w = pack2(Ls[cc + 6][d], Ls[cc + 7][d]);
    *(uint4*)&WhT[(long)z * DD * NN + (long)(d0 + d) * NN + i0 + cc] = q;
  }
}

// ---------------- K5: scores (f16 S) + partial column-softmax stats ----------
__global__ __launch_bounds__(256) void k_scores(const int* __restrict__ madj,
                                                const int* __restrict__ adj,
                                                const float* __restrict__ s0,
                                                const float* __restrict__ s1,
                                                const float* __restrict__ r0,
                                                const float* __restrict__ r1,
                                                ushort* __restrict__ Sh,
                                                float* __restrict__ pm,
                                                float* __restrict__ pl) {
  int b = blockIdx.x, c = blockIdx.y;
  int tid = threadIdx.x;
  int j4 = tid * 4;
  int i0 = c * ICH;
  __shared__ float s0c[ICH];
  __shared__ float r0c[RR][ICH];
  if (tid < (RR + 1) * ICH) {
    int v = tid / ICH, i = tid % ICH;
    float x = (v == 0) ? s0[b * NN + i0 + i] : r0[(v - 1) * BN + b * NN + i0 + i];
    if (v == 0) s0c[i] = x; else r0c[v - 1][i] = x;
  }
  __syncthreads();
  float4 s14 = *(const float4*)&s1[b * NN + j4];
  float rel[ICH][4] = {};
#pragma unroll 1
  for (int r = 0; r < RR; ++r) {
    float4 r1v = *(const float4*)&r1[r * BN + b * NN + j4];
#pragma unroll
    for (int i = 0; i < ICH; ++i) {
      int4v mv = __builtin_nontemporal_load(
          (const int4v*)&madj[(((long)r * BB + b) * NN + i0 + i) * NN + j4]);
      float r0v = r0c[r][i];
      float t0 = r0v + r1v.x; t0 = t0 >= 0.f ? t0 : 0.2f * t0;
      float t1 = r0v + r1v.y; t1 = t1 >= 0.f ? t1 : 0.2f * t1;
      float t2 = r0v + r1v.z; t2 = t2 >= 0.f ? t2 : 0.2f * t2;
      float t3 = r0v + r1v.w; t3 = t3 >= 0.f ? t3 : 0.2f * t3;
      if (mv.x > 0) rel[i][0] += t0;
      if (mv.y > 0) rel[i][1] += t1;
      if (mv.z > 0) rel[i][2] += t2;
      if (mv.w > 0) rel[i][3] += t3;
    }
  }
  float m0 = -3.0e38f, m1 = -3.0e38f, m2 = -3.0e38f, m3 = -3.0e38f;
  float l0 = 0.f, l1 = 0.f, l2 = 0.f, l3 = 0.f;
#pragma unroll
  for (int i = 0; i < ICH; ++i) {
    int4v av = __builtin_nontemporal_load(
        (const int4v*)&adj[((long)b * NN + i0 + i) * NN + j4]);
    float s0v = s0c[i];
    float4 sc;
    { float e = s0v + s14.x; e = e >= 0.f ? e : 0.2f * e;
      sc.x = (av.x > 0 ? e : -9e15f) + 0.01f * rel[i][0]; }
    { float e = s0v + s14.y; e = e >= 0.f ? e : 0.2f * e;
      sc.y = (av.y > 0 ? e : -9e15f) + 0.01f * rel[i][1]; }
    { float e = s0v + s14.z; e = e >= 0.f ? e : 0.2f * e;
      sc.z = (av.z > 0 ? e : -9e15f) + 0.01f * rel[i][2]; }
    { float e = s0v + s14.w; e = e >= 0.f ? e : 0.2f * e;
      sc.w = (av.w > 0 ? e : -9e15f) + 0.01f * rel[i][3]; }
    uint2 so;
    so.x = (uint)f2h(sc.x) | ((uint)f2h(sc.y) << 16);
    so.y = (uint)f2h(sc.z) | ((uint)f2h(sc.w) << 16);
    *(uint2*)&Sh[((long)b * NN + i0 + i) * NN + j4] = so;
    float nm;
    nm = fmaxf(m0, sc.x); l0 = l0 * __expf(m0 - nm) + __expf(sc.x - nm); m0 = nm;
    nm = fmaxf(m1, sc.y); l1 = l1 * __expf(m1 - nm) + __expf(sc.y - nm); m1 = nm;
    nm = fmaxf(m2, sc.z); l2 = l2 * __expf(m2 - nm) + __expf(sc.z - nm); m2 = nm;
    nm = fmaxf(m3, sc.w); l3 = l3 * __expf(m3 - nm) + __expf(sc.w - nm); m3 = nm;
  }
  *(float4*)&pm[(long)c * BN + b * NN + j4] = make_float4(m0, m1, m2, m3);
  *(float4*)&pl[(long)c * BN + b * NN + j4] = make_float4(l0, l1, l2, l3);
}

// ---------------- K6: combine partial stats (16 thr/col, tree) ----------
__global__ __launch_bounds__(256) void k_combine(const float* __restrict__ pm,
                                                 const float* __restrict__ pl,
                                                 float* __restrict__ mf,
                                                 float* __restrict__ li) {
  __shared__ float sm_m[256], sm_l[256];
  int tid = threadIdx.x;
  int col_l = tid & 15, seg = tid >> 4;
  int col = blockIdx.x * 16 + col_l;
  float m = -3.0e38f, l = 0.f;
#pragma unroll
  for (int q = 0; q < 8; ++q) {
    int c = seg * 8 + q;
    float mc = pm[(long)c * BN + col];
    float lc = pl[(long)c * BN + col];
    float nm = fmaxf(m, mc);
    l = l * __expf(m - nm) + lc * __expf(mc - nm);
    m = nm;
  }
  sm_m[tid] = m; sm_l[tid] = l;
  __syncthreads();
  for (int s = 8; s; s >>= 1) {
    if (seg < s) {
      float ma = sm_m[tid], la = sm_l[tid];
      float mb = sm_m[tid + s * 16], lb = sm_l[tid + s * 16];
      float nm = fmaxf(ma, mb);
      sm_m[tid] = nm;
      sm_l[tid] = la * __expf(ma - nm) + lb * __expf(mb - nm);
    }
    __syncthreads();
  }
  if (seg == 0) {
    mf[col] = sm_m[tid];
    li[col] = 1.0f / sm_l[tid];
  }
}

// ---------------- K7: out = elu( P @ Wh1 ), P from f16 S; BM=64 BN=128 ------
__global__ __launch_bounds__(256) void k_av(const ushort* __restrict__ Sh,
                                            const float* __restrict__ mf,
                                            const float* __restrict__ li,
                                            const ushort* __restrict__ WhT,
                                            float* __restrict__ out) {
  __shared__ uint4 AswQ[64 * 8];
  __shared__ uint4 BswQ[128 * 8];
  int b = blockIdx.z;
  int i0 = blockIdx.y * 64;
  int n0 = blockIdx.x * 128;
  const ushort* Sb = Sh + (long)b * NN * NN;
  const ushort* Bb = WhT + (long)b * DD * NN;
  const float* mfb = mf + (long)b * NN;
  const float* lib = li + (long)b * NN;
  int tid = threadIdx.x;
  int r = tid >> 3, cs = tid & 7;
  int lane = tid & 63, wid = tid >> 6;
  int wm = wid >> 1, wn = wid & 1;
  int lr = lane & 15, g = lane >> 4;
  f32x4 acc[2][4] = {};
  for (int k0 = 0; k0 < NN; k0 += 64) {
#pragma unroll
    for (int p = 0; p < 2; ++p) {
      int row = p * 32 + r;
      uint4 sv = *(const uint4*)(Sb + (long)(i0 + row) * NN + k0 + cs * 8);
      half8v hv = *reinterpret_cast<const half8v*>(&sv);
      const float* mp = mfb + k0 + cs * 8;
      const float* lp = lib + k0 + cs * 8;
      float4 m0 = *(const float4*)mp, m1 = *(const float4*)(mp + 4);
      float4 l0 = *(const float4*)lp, l1 = *(const float4*)(lp + 4);
      float v0 = __expf((float)hv[0] - m0.x) * l0.x;
      float v1 = __expf((float)hv[1] - m0.y) * l0.y;
      float v2 = __expf((float)hv[2] - m0.z) * l0.z;
      float v3 = __expf((float)hv[3] - m0.w) * l0.w;
      float v4 = __expf((float)hv[4] - m1.x) * l1.x;
      float v5 = __expf((float)hv[5] - m1.y) * l1.y;
      float v6 = __expf((float)hv[6] - m1.z) * l1.z;
      float v7 = __expf((float)hv[7] - m1.w) * l1.w;
      uint4 q;
      q.x = pack2(v0, v1); q.y = pack2(v2, v3);
      q.z = pack2(v4, v5); q.w = pack2(v6, v7);
      AswQ[row * 8 + (cs ^ (row & 7))] = q;
    }
#pragma unroll
    for (int p = 0; p < 4; ++p) {
      int row = p * 32 + r;
      uint4 q = *(const uint4*)(Bb + (long)(n0 + row) * NN + k0 + cs * 8);
      BswQ[row * 8 + (cs ^ (row & 7))] = q;
    }
    __syncthreads();
#pragma unroll
    for (int ks = 0; ks < 2; ++ks) {
      short8v af[2], bfr[4];
      int slot = ks * 4 + g;
#pragma unroll
      for (int mi = 0; mi < 2; ++mi) {
        int row = wm * 32 + mi * 16 + lr;
        af[mi] = *reinterpret_cast<const short8v*>(&AswQ[row * 8 + (slot ^ (row & 7))]);
      }
#pragma unroll
      for (int ni = 0; ni < 4; ++ni) {
        int row = wn * 64 + ni * 16 + lr;
        bfr[ni] = *reinterpret_cast<const short8v*>(&BswQ[row * 8 + (slot ^ (row & 7))]);
      }
#pragma unroll
      for (int mi = 0; mi < 2; ++mi)
#pragma unroll
        for (int ni = 0; ni < 4; ++ni)
          acc[mi][ni] = __builtin_amdgcn_mfma_f32_16x16x32_bf16(af[mi], bfr[ni], acc[mi][ni], 0, 0, 0);
    }
    __syncthreads();
  }
#pragma unroll
  for (int mi = 0; mi < 2; ++mi)
#pragma unroll
    for (int ni = 0; ni < 4; ++ni)
#pragma unroll
      for (int q = 0; q < 4; ++q) {
        int row = i0 + wm * 32 + mi * 16 + g * 4 + q;
        int col = n0 + wn * 64 + ni * 16 + lr;
        float x = acc[mi][ni][q];
        x = x > 0.f ? x : expm1f(x);
        out[((long)b * NN + row) * DD + col] = x;
      }
}

extern "C" void kernel_launch(void* const* d_in, const int* in_sizes, int n_in,
                              void* d_out, int out_size, void* d_ws, size_t ws_size,
                              hipStream_t stream) {
  const float* h0 = (const float*)d_in[0];
  const float* h1 = (const float*)d_in[1];
  const int* madj = (const int*)d_in[2];
  const int* adj = (const int*)d_in[3];
  const float* W = (const float*)d_in[4];
  const float* a = (const float*)d_in[5];
  const float* A_rel = (const float*)d_in[6];
  float* out = (float*)d_out;

  float* ws = (float*)d_ws;
  float* Wh1 = ws;                          // 2,097,152 f32
  float* s0 = Wh1 + (size_t)BN * DD;        // 8192
  float* s1 = s0 + BN;
  float* r0 = s1 + BN;                      // 98304
  float* r1 = r0 + RR * BN;
  float* pm = r1 + RR * BN;                 // 1,048,576
  float* pl = pm + (size_t)CCH * BN;        // 1,048,576
  float* mf = pl + (size_t)CCH * BN;        // 8192
  float* li = mf + BN;
  float* Vt = li + BN;                      // 6656
  ushort* WTb = (ushort*)(Vt + 26 * DD);    // 65,536 ushort
  ushort* WhT = WTb + DD * DD;              // 2,097,152 ushort
  ushort* Sh = WhT + (size_t)BB * DD * NN;  // 8,388,608 ushort (f16)

  k_prep<<<68, 256, 0, stream>>>(W, a, A_rel, WTb, Vt);
  k_proj<<<(2 * BN) / 4, 256, 0, stream>>>(h0, h1, Vt, s0, s1, r0, r1);
  k_scores<<<dim3(BB, CCH), 256, 0, stream>>>(madj, adj, s0, s1, r0, r1, Sh, pm, pl);
  k_mm_wh1<<<dim3(2, BN / 64), 256, 0, stream>>>(h1, WTb, Wh1);
  k_transWh<<<dim3(4, 16, 8), 256, 0, stream>>>(Wh1, WhT);
  k_combine<<<512, 256, 0, stream>>>(pm, pl, mf, li);
  k_av<<<dim3(2, NN / 64, BB), 256, 0, stream>>>(Sh, mf, li, WhT, out);
}

// Round 7
// 171.040 us; speedup vs baseline: 1.4012x; 1.0463x over previous
//
#include <hip/hip_runtime.h>
#include <hip/hip_bf16.h>
#include <hip/hip_fp16.h>

#define BB 8
#define NN 1024
#define DD 256
#define RR 12
#define BN (BB * NN)  // 8192
#define ICH 8
#define CCH (NN / ICH)  // 128

typedef __attribute__((ext_vector_type(8))) short short8v;
typedef __attribute__((ext_vector_type(8))) _Float16 half8v;
typedef __attribute__((ext_vector_type(4))) float f32x4;
typedef __attribute__((ext_vector_type(4))) int int4v;

static __device__ __forceinline__ ushort f2bf(float f) {
  union { float f; uint u; } v; v.f = f;
  uint r = v.u + 0x7FFF + ((v.u >> 16) & 1);
  return (ushort)(r >> 16);
}
static __device__ __forceinline__ uint pack2(float a, float b) {
  return (uint)f2bf(a) | ((uint)f2bf(b) << 16);
}
static __device__ __forceinline__ ushort f2h(float f) {
  __half h = __float2half(f);  // RTN
  union { __half h; ushort u; } v; v.h = h;
  return v.u;
}

// ---------------- K1: prepW transpose (blocks 0..15) + Vt (16..67) ----------
__global__ __launch_bounds__(256) void k_prep(const float* __restrict__ W,
                                              const float* __restrict__ a,
                                              const float* __restrict__ A_rel,
                                              ushort* __restrict__ WTb,
                                              float* __restrict__ Vt) {
  __shared__ float Ls[64][65];
  int blk = blockIdx.x, tid = threadIdx.x;
  if (blk < 16) {
    int k0 = (blk & 3) * 64, d0 = (blk >> 2) * 64;
    int rr = tid >> 4, c = (tid & 15) * 4;
#pragma unroll
    for (int p = 0; p < 4; ++p) {
      int row = p * 16 + rr;
      float4 v = *(const float4*)&W[(k0 + row) * DD + d0 + c];
      Ls[row][c] = v.x; Ls[row][c + 1] = v.y; Ls[row][c + 2] = v.z; Ls[row][c + 3] = v.w;
    }
    __syncthreads();
    int r2 = tid >> 3, cc = (tid & 7) * 8;
#pragma unroll
    for (int p = 0; p < 2; ++p) {
      int d = p * 32 + r2;
      uint4 q;
      q.x = pack2(Ls[cc + 0][d], Ls[cc + 1][d]);
      q.y = pack2(Ls[cc + 2][d], Ls[cc + 3][d]);
      q.z = pack2(Ls[cc + 4][d], Ls[cc + 5][d]);
      q.w = pack2(Ls[cc + 6][d], Ls[cc + 7][d]);
      *(uint4*)&WTb[(d0 + d) * DD + k0 + cc] = q;
    }
  } else {
    int idx = blk - 16;
    int half = idx >= 26 ? 1 : 0;
    int c = idx - half * 26;
    if (c >= 13) return;
    int lane = tid & 63, w = tid >> 6;
    const float* X = (c == 0) ? &a[half * DD] : &A_rel[(c - 1) * 2 * DD + half * DD];
    float4 x4 = *(const float4*)&X[lane * 4];
    for (int kk = 0; kk < 64; ++kk) {
      int k = kk * 4 + w;
      float4 w4 = *(const float4*)&W[k * DD + lane * 4];
      float p = w4.x * x4.x + w4.y * x4.y + w4.z * x4.z + w4.w * x4.w;
#pragma unroll
      for (int off = 32; off; off >>= 1) p += __shfl_xor(p, off);
      if (lane == 0) Vt[(half * 13 + c) * DD + k] = p;
    }
  }
}

// ---------------- K2: per-node projections from h and Vt ----------------
__global__ __launch_bounds__(256) void k_proj(const float* __restrict__ h0,
                                              const float* __restrict__ h1,
                                              const float* __restrict__ Vt,
                                              float* __restrict__ s0, float* __restrict__ s1,
                                              float* __restrict__ r0, float* __restrict__ r1) {
  int wid = (blockIdx.x * 256 + threadIdx.x) >> 6;  // 0..16383
  int lane = threadIdx.x & 63;
  int mat = wid >> 13;
  int row = wid & (BN - 1);
  const float* h = mat ? h1 : h0;
  float4 h4 = *(const float4*)&h[(long)row * DD + lane * 4];
  float p[13];
#pragma unroll
  for (int c = 0; c < 13; ++c) {
    float4 v4 = *(const float4*)&Vt[(mat * 13 + c) * DD + lane * 4];
    p[c] = h4.x * v4.x + h4.y * v4.y + h4.z * v4.z + h4.w * v4.w;
  }
#pragma unroll
  for (int off = 32; off; off >>= 1)
#pragma unroll
    for (int c = 0; c < 13; ++c) p[c] += __shfl_xor(p[c], off);
  if (lane == 0) {
    if (mat == 0) {
      s0[row] = p[0];
      for (int c = 1; c < 13; ++c) r0[(c - 1) * BN + row] = p[c];
    } else {
      s1[row] = p[0];
      for (int c = 1; c < 13; ++c) r1[(c - 1) * BN + row] = p[c];
    }
  }
}

// ---------------- K3: scores -> U = exp(S-4) (f16) + column partial sums ----
__global__ __launch_bounds__(256) void k_scores(const int* __restrict__ madj,
                                                const int* __restrict__ adj,
                                                const float* __restrict__ s0,
                                                const float* __restrict__ s1,
                                                const float* __restrict__ r0,
                                                const float* __restrict__ r1,
                                                ushort* __restrict__ U,
                                                float* __restrict__ psum) {
  int b = blockIdx.x, c = blockIdx.y;
  int tid = threadIdx.x;
  int j4 = tid * 4;
  int i0 = c * ICH;
  __shared__ float s0c[ICH];
  __shared__ float r0c[RR][ICH];
  if (tid < (RR + 1) * ICH) {
    int v = tid / ICH, i = tid % ICH;
    float x = (v == 0) ? s0[b * NN + i0 + i] : r0[(v - 1) * BN + b * NN + i0 + i];
    if (v == 0) s0c[i] = x; else r0c[v - 1][i] = x;
  }
  __syncthreads();
  float4 s14 = *(const float4*)&s1[b * NN + j4];
  float rel[ICH][4] = {};
#pragma unroll 1
  for (int r = 0; r < RR; ++r) {
    float4 r1v = *(const float4*)&r1[r * BN + b * NN + j4];
#pragma unroll
    for (int i = 0; i < ICH; ++i) {
      int4v mv = __builtin_nontemporal_load(
          (const int4v*)&madj[(((long)r * BB + b) * NN + i0 + i) * NN + j4]);
      float r0v = r0c[r][i];
      float t0 = r0v + r1v.x; t0 = t0 >= 0.f ? t0 : 0.2f * t0;
      float t1 = r0v + r1v.y; t1 = t1 >= 0.f ? t1 : 0.2f * t1;
      float t2 = r0v + r1v.z; t2 = t2 >= 0.f ? t2 : 0.2f * t2;
      float t3 = r0v + r1v.w; t3 = t3 >= 0.f ? t3 : 0.2f * t3;
      if (mv.x > 0) rel[i][0] += t0;
      if (mv.y > 0) rel[i][1] += t1;
      if (mv.z > 0) rel[i][2] += t2;
      if (mv.w > 0) rel[i][3] += t3;
    }
  }
  float l0 = 0.f, l1 = 0.f, l2 = 0.f, l3 = 0.f;
#pragma unroll
  for (int i = 0; i < ICH; ++i) {
    int4v av = __builtin_nontemporal_load(
        (const int4v*)&adj[((long)b * NN + i0 + i) * NN + j4]);
    float s0v = s0c[i];
    float u0, u1, u2, u3;
    { float e = s0v + s14.x; e = e >= 0.f ? e : 0.2f * e;
      u0 = __expf((av.x > 0 ? e : -9e15f) + 0.01f * rel[i][0] - 4.0f); }
    { float e = s0v + s14.y; e = e >= 0.f ? e : 0.2f * e;
      u1 = __expf((av.y > 0 ? e : -9e15f) + 0.01f * rel[i][1] - 4.0f); }
    { float e = s0v + s14.z; e = e >= 0.f ? e : 0.2f * e;
      u2 = __expf((av.z > 0 ? e : -9e15f) + 0.01f * rel[i][2] - 4.0f); }
    { float e = s0v + s14.w; e = e >= 0.f ? e : 0.2f * e;
      u3 = __expf((av.w > 0 ? e : -9e15f) + 0.01f * rel[i][3] - 4.0f); }
    uint2 so;
    so.x = (uint)f2h(u0) | ((uint)f2h(u1) << 16);
    so.y = (uint)f2h(u2) | ((uint)f2h(u3) << 16);
    *(uint2*)&U[((long)b * NN + i0 + i) * NN + j4] = so;
    l0 += u0; l1 += u1; l2 += u2; l3 += u3;
  }
  *(float4*)&psum[(long)c * BN + b * NN + j4] = make_float4(l0, l1, l2, l3);
}

// ---------------- K4: WhT = bf16((h1 @ W)^T), fused MFMA + transpose --------
__global__ __launch_bounds__(256) void k_mm_wh1(const float* __restrict__ h1,
                                                const ushort* __restrict__ WTb,
                                                ushort* __restrict__ WhT) {
  __shared__ __align__(16) char smraw[24576];
  uint4* AswQ = (uint4*)smraw;                 // 64*8 uint4 = 8 KB
  uint4* BswQ = (uint4*)(smraw + 8192);        // 128*8 uint4 = 16 KB
  typedef ushort LtRow[72];
  LtRow* Lt = (LtRow*)smraw;                   // 128 x 72 ushort = 18 KB (reuse)
  int n0 = blockIdx.x * 128, i0 = blockIdx.y * 64;
  int tid = threadIdx.x;
  int r = tid >> 3, cs = tid & 7;
  int lane = tid & 63, wid = tid >> 6;
  int wm = wid >> 1, wn = wid & 1;
  int lr = lane & 15, g = lane >> 4;
  f32x4 acc[2][4] = {};
  for (int k0 = 0; k0 < DD; k0 += 64) {
#pragma unroll
    for (int p = 0; p < 2; ++p) {
      int row = p * 32 + r;
      const float* src = h1 + (long)(i0 + row) * DD + k0 + cs * 8;
      float4 v0 = *(const float4*)src;
      float4 v1 = *(const float4*)(src + 4);
      uint4 q;
      q.x = pack2(v0.x, v0.y); q.y = pack2(v0.z, v0.w);
      q.z = pack2(v1.x, v1.y); q.w = pack2(v1.z, v1.w);
      AswQ[row * 8 + (cs ^ (row & 7))] = q;
    }
#pragma unroll
    for (int p = 0; p < 4; ++p) {
      int row = p * 32 + r;
      uint4 q = *(const uint4*)(WTb + (long)(n0 + row) * DD + k0 + cs * 8);
      BswQ[row * 8 + (cs ^ (row & 7))] = q;
    }
    __syncthreads();
#pragma unroll
    for (int ks = 0; ks < 2; ++ks) {
      short8v af[2], bfr[4];
      int slot = ks * 4 + g;
#pragma unroll
      for (int mi = 0; mi < 2; ++mi) {
        int row = wm * 32 + mi * 16 + lr;
        af[mi] = *reinterpret_cast<const short8v*>(&AswQ[row * 8 + (slot ^ (row & 7))]);
      }
#pragma unroll
      for (int ni = 0; ni < 4; ++ni) {
        int row = wn * 64 + ni * 16 + lr;
        bfr[ni] = *reinterpret_cast<const short8v*>(&BswQ[row * 8 + (slot ^ (row & 7))]);
      }
#pragma unroll
      for (int mi = 0; mi < 2; ++mi)
#pragma unroll
        for (int ni = 0; ni < 4; ++ni)
          acc[mi][ni] = __builtin_amdgcn_mfma_f32_16x16x32_bf16(af[mi], bfr[ni], acc[mi][ni], 0, 0, 0);
    }
    __syncthreads();
  }
  // retile acc (i x d) -> Lt[d][i] bf16
#pragma unroll
  for (int mi = 0; mi < 2; ++mi)
#pragma unroll
    for (int ni = 0; ni < 4; ++ni) {
      int d = wn * 64 + ni * 16 + lr;
      int ib = wm * 32 + mi * 16 + g * 4;
      uint2 w;
      w.x = pack2(acc[mi][ni][0], acc[mi][ni][1]);
      w.y = pack2(acc[mi][ni][2], acc[mi][ni][3]);
      *(uint2*)&Lt[d][ib] = w;
    }
  __syncthreads();
  int b = i0 >> 10, il = i0 & 1023;
#pragma unroll
  for (int p = 0; p < 4; ++p) {
    int row = (tid >> 3) + p * 32;   // 0..127
    int ch = (tid & 7) * 8;          // 0..56
    uint4 q = *(uint4*)&Lt[row][ch];
    *(uint4*)&WhT[((long)b * DD + n0 + row) * NN + il + ch] = q;
  }
}

// ---------------- K5: li = 1 / sum_c psum ----------------
__global__ __launch_bounds__(256) void k_combine(const float* __restrict__ psum,
                                                 float* __restrict__ li) {
  __shared__ float sm_l[256];
  int tid = threadIdx.x;
  int col_l = tid & 15, seg = tid >> 4;
  int col = blockIdx.x * 16 + col_l;
  float l = 0.f;
#pragma unroll
  for (int q = 0; q < 8; ++q) l += psum[(long)(seg * 8 + q) * BN + col];
  sm_l[tid] = l;
  __syncthreads();
  for (int s = 8; s; s >>= 1) {
    if (seg < s) sm_l[tid] += sm_l[tid + s * 16];
    __syncthreads();
  }
  if (seg == 0) li[col] = 1.0f / sm_l[tid];
}

// ---------------- K6: out = elu( (U*li) @ WhT^T ), BM=64 BN=128 ------------
__global__ __launch_bounds__(256) void k_av(const ushort* __restrict__ U,
                                            const float* __restrict__ li,
                                            const ushort* __restrict__ WhT,
                                            float* __restrict__ out) {
  __shared__ uint4 AswQ[64 * 8];
  __shared__ uint4 BswQ[128 * 8];
  int b = blockIdx.z;
  int i0 = blockIdx.y * 64;
  int n0 = blockIdx.x * 128;
  const ushort* Sb = U + (long)b * NN * NN;
  const ushort* Bb = WhT + (long)b * DD * NN;
  const float* lib = li + (long)b * NN;
  int tid = threadIdx.x;
  int r = tid >> 3, cs = tid & 7;
  int lane = tid & 63, wid = tid >> 6;
  int wm = wid >> 1, wn = wid & 1;
  int lr = lane & 15, g = lane >> 4;
  f32x4 acc[2][4] = {};
  for (int k0 = 0; k0 < NN; k0 += 64) {
#pragma unroll
    for (int p = 0; p < 2; ++p) {
      int row = p * 32 + r;
      uint4 sv = *(const uint4*)(Sb + (long)(i0 + row) * NN + k0 + cs * 8);
      half8v hv = *reinterpret_cast<const half8v*>(&sv);
      const float* lp = lib + k0 + cs * 8;
      float4 l0 = *(const float4*)lp, l1 = *(const float4*)(lp + 4);
      float v0 = (float)hv[0] * l0.x;
      float v1 = (float)hv[1] * l0.y;
      float v2 = (float)hv[2] * l0.z;
      float v3 = (float)hv[3] * l0.w;
      float v4 = (float)hv[4] * l1.x;
      float v5 = (float)hv[5] * l1.y;
      float v6 = (float)hv[6] * l1.z;
      float v7 = (float)hv[7] * l1.w;
      uint4 q;
      q.x = pack2(v0, v1); q.y = pack2(v2, v3);
      q.z = pack2(v4, v5); q.w = pack2(v6, v7);
      AswQ[row * 8 + (cs ^ (row & 7))] = q;
    }
#pragma unroll
    for (int p = 0; p < 4; ++p) {
      int row = p * 32 + r;
      uint4 q = *(const uint4*)(Bb + (long)(n0 + row) * NN + k0 + cs * 8);
      BswQ[row * 8 + (cs ^ (row & 7))] = q;
    }
    __syncthreads();
#pragma unroll
    for (int ks = 0; ks < 2; ++ks) {
      short8v af[2], bfr[4];
      int slot = ks * 4 + g;
#pragma unroll
      for (int mi = 0; mi < 2; ++mi) {
        int row = wm * 32 + mi * 16 + lr;
        af[mi] = *reinterpret_cast<const short8v*>(&AswQ[row * 8 + (slot ^ (row & 7))]);
      }
#pragma unroll
      for (int ni = 0; ni < 4; ++ni) {
        int row = wn * 64 + ni * 16 + lr;
        bfr[ni] = *reinterpret_cast<const short8v*>(&BswQ[row * 8 + (slot ^ (row & 7))]);
      }
#pragma unroll
      for (int mi = 0; mi < 2; ++mi)
#pragma unroll
        for (int ni = 0; ni < 4; ++ni)
          acc[mi][ni] = __builtin_amdgcn_mfma_f32_16x16x32_bf16(af[mi], bfr[ni], acc[mi][ni], 0, 0, 0);
    }
    __syncthreads();
  }
#pragma unroll
  for (int mi = 0; mi < 2; ++mi)
#pragma unroll
    for (int ni = 0; ni < 4; ++ni)
#pragma unroll
      for (int q = 0; q < 4; ++q) {
        int row = i0 + wm * 32 + mi * 16 + g * 4 + q;
        int col = n0 + wn * 64 + ni * 16 + lr;
        float x = acc[mi][ni][q];
        x = x > 0.f ? x : expm1f(x);
        out[((long)b * NN + row) * DD + col] = x;
      }
}

extern "C" void kernel_launch(void* const* d_in, const int* in_sizes, int n_in,
                              void* d_out, int out_size, void* d_ws, size_t ws_size,
                              hipStream_t stream) {
  const float* h0 = (const float*)d_in[0];
  const float* h1 = (const float*)d_in[1];
  const int* madj = (const int*)d_in[2];
  const int* adj = (const int*)d_in[3];
  const float* W = (const float*)d_in[4];
  const float* a = (const float*)d_in[5];
  const float* A_rel = (const float*)d_in[6];
  float* out = (float*)d_out;

  float* ws = (float*)d_ws;
  float* s0 = ws;                           // 8192
  float* s1 = s0 + BN;
  float* r0 = s1 + BN;                      // 98304
  float* r1 = r0 + RR * BN;
  float* psum = r1 + RR * BN;               // 1,048,576
  float* li = psum + (size_t)CCH * BN;      // 8192
  float* Vt = li + BN;                      // 6656
  ushort* WTb = (ushort*)(Vt + 26 * DD);    // 65,536 ushort
  ushort* WhT = WTb + DD * DD;              // 2,097,152 ushort
  ushort* Uh = WhT + (size_t)BB * DD * NN;  // 8,388,608 ushort (f16)

  k_prep<<<68, 256, 0, stream>>>(W, a, A_rel, WTb, Vt);
  k_proj<<<(2 * BN) / 4, 256, 0, stream>>>(h0, h1, Vt, s0, s1, r0, r1);
  k_scores<<<dim3(BB, CCH), 256, 0, stream>>>(madj, adj, s0, s1, r0, r1, Uh, psum);
  k_mm_wh1<<<dim3(2, BN / 64), 256, 0, stream>>>(h1, WTb, WhT);
  k_combine<<<512, 256, 0, stream>>>(psum, li);
  k_av<<<dim3(2, NN / 64, BB), 256, 0, stream>>>(Uh, li, WhT, out);
}